// Round 17
// baseline (216.224 us; speedup 1.0000x reference)
//
#include <hip/hip_runtime.h>
#include <math.h>

// DecoderCell — Round 17: R16 with the zero-loop SIZE fix. us4 is 8 bytes
// (4 x ushort), not 16: sGn needs 13824/8 = 1728 chunk-writes, not 864.
// R16 zeroed only rows 0-15; rows 16-31 cols 200-215 stayed uninit-NaN and
// the factor GEMM's k>=200 fragments produced NaN*0=NaN. One-line fix.

#define XD 272
#define HD 420

typedef unsigned short ushort_t;
typedef __attribute__((ext_vector_type(8))) short bf8;
typedef __attribute__((ext_vector_type(4))) float f4;
typedef __attribute__((ext_vector_type(4))) unsigned short us4;

// ws layout (bf16 element offsets)
#define WS_W1 0         // con_w_ih [384][320]
#define WS_W2 122880    // con_w_hh [384][128]
#define WS_W3 172032    // gen_w_ih [608][32]  (K 20->32 pad, rows 600-607 zero)
#define WS_W4 191488    // gen_w_hh [608][224] (K 200->224 pad, rows 600-607 zero)
#define WS_W5 327680    // normed fac_w [64][224] (K pad zero)

#define STA 328
#define STG 216
#define STH 136

__device__ __forceinline__ ushort_t f2bf(float f) {
  union { float f; unsigned u; } v; v.f = f;
  unsigned r = v.u + 0x7FFFu + ((v.u >> 16) & 1u);
  return (ushort_t)(r >> 16);
}
__device__ __forceinline__ float bf2f(ushort_t u) {
  union { unsigned u; float f; } v; v.u = ((unsigned)u) << 16; return v.f;
}
__device__ __forceinline__ us4 f2bf4(f4 v) {
  us4 b; b.x = f2bf(v.x); b.y = f2bf(v.y); b.z = f2bf(v.z); b.w = f2bf(v.w); return b;
}
__device__ __forceinline__ f4 bf2f4(us4 b) {
  f4 v; v.x = bf2f(b.x); v.y = bf2f(b.y); v.z = bf2f(b.z); v.w = bf2f(b.w); return v;
}
__device__ __forceinline__ float rcpf(float x) { return __builtin_amdgcn_rcpf(x); }
__device__ __forceinline__ float sigf(float x) { return rcpf(1.0f + __expf(-x)); }
__device__ __forceinline__ float tanhf_(float x) {
  return 1.0f - 2.0f * rcpf(1.0f + __expf(2.0f * x));
}

#define MFMA(a, b, c) __builtin_amdgcn_mfma_f32_16x16x32_bf16((a), (b), (c), 0, 0, 0)

__global__ void prep_w(const float* __restrict__ cw1, const float* __restrict__ cw2,
                       const float* __restrict__ gw3, const float* __restrict__ gw4,
                       ushort_t* __restrict__ ws) {
  int tid = blockIdx.x * blockDim.x + threadIdx.x;
  int np = gridDim.x * blockDim.x;
  for (int i = tid; i < 384 * 320; i += np) ws[WS_W1 + i] = f2bf(cw1[i]);
  for (int i = tid; i < 384 * 128; i += np) ws[WS_W2 + i] = f2bf(cw2[i]);
  for (int i = tid; i < 608 * 32; i += np) {
    int n = i >> 5, k = i & 31;
    ws[WS_W3 + i] = (n < 600 && k < 20) ? f2bf(gw3[n * 20 + k]) : (ushort_t)0;
  }
  for (int i = tid; i < 608 * 224; i += np) {
    int n = i / 224, k = i - n * 224;
    ws[WS_W4 + i] = (n < 600 && k < 200) ? f2bf(gw4[n * 200 + k]) : (ushort_t)0;
  }
}

__global__ void prep_fac(const float* __restrict__ fw, ushort_t* __restrict__ ws) {
  int n = blockIdx.x;   // 64 rows
  int l = threadIdx.x;  // 64 lanes
  float ss = 0.f;
  for (int k = l; k < 200; k += 64) { float v = fw[n * 200 + k]; ss = fmaf(v, v, ss); }
  for (int off = 32; off; off >>= 1) ss += __shfl_down(ss, off, 64);
  ss = __shfl(ss, 0, 64);
  float inv = 1.0f / fmaxf(sqrtf(ss), 1e-12f);
  for (int k = l; k < 224; k += 64)
    ws[WS_W5 + n * 224 + k] = (k < 200) ? f2bf(fw[n * 200 + k] * inv) : (ushort_t)0;
}

// ================= K1: controller GRU + co linear + reparam =================
__global__ __launch_bounds__(256, 4) void con_kernel(
    const float* __restrict__ x, const float* __restrict__ h0,
    const float* __restrict__ eps,
    const float* __restrict__ con_b_ih, const float* __restrict__ con_b_hh,
    const float* __restrict__ co_w, const float* __restrict__ co_b,
    const ushort_t* __restrict__ ws, float* __restrict__ out)
{
  __shared__ __align__(16) unsigned char spool[29696];
  ushort_t* sA  = (ushort_t*)(spool);          // [32][328] con_input
  ushort_t* sR2 = (ushort_t*)(spool + 20992);  // [32][136] con_state

  const int tid = threadIdx.x;
  const int rbase = blockIdx.x * 32;
  const int lane = tid & 63;
  const int w = tid >> 6;             // 0..3
  const int bn = lane & 15;
  const int kq = (lane >> 4) << 3;
  const int qrow = (lane >> 4) << 2;

  // ph1: stage con_input + con_state; ext -> out direct
  #pragma unroll
  for (int it = 0; it < 8; ++it) {  // x[:,0:256] -> sA
    int idx = tid + it * 256;
    int r = idx >> 6, c4 = (idx & 63) << 2;
    f4 v = *(const f4*)&x[(size_t)(rbase + r) * XD + c4];
    *(us4*)&sA[r * STA + c4] = f2bf4(v);
  }
  if (tid < 128) {  // x[:,256:272] -> out[340:356] (gen_input ext, f32)
    int r = tid >> 2, e = (tid & 3) << 2;
    f4 v = *(const f4*)&x[(size_t)(rbase + r) * XD + 256 + e];
    *(f4*)&out[(size_t)(rbase + r) * HD + 340 + e] = v;
  }
  #pragma unroll
  for (int it = 0; it < 4; ++it) {  // h0[:,200:328] -> sR2
    int idx = tid + it * 256;
    int r = idx >> 5, c4 = (idx & 31) << 2;
    f4 v = *(const f4*)&h0[(size_t)(rbase + r) * HD + 200 + c4];
    *(us4*)&sR2[r * STH + c4] = f2bf4(v);
  }
  #pragma unroll
  for (int it = 0; it < 2; ++it) {  // h0[:,356:420] -> sA cols 256..320
    int idx = tid + it * 256;
    int r = idx >> 4, c4 = (idx & 15) << 2;
    f4 v = *(const f4*)&h0[(size_t)(rbase + r) * HD + 356 + c4];
    *(us4*)&sA[r * STA + 256 + c4] = f2bf4(v);
  }
  __syncthreads();  // B1

  // ph2: con GEMMs, 2 col-tiles/wave x 2 row-tiles
  f4 aR[2][2], aZ[2][2], aN[2][2], aHN[2][2];
  #pragma unroll
  for (int ti = 0; ti < 2; ++ti)
    #pragma unroll
    for (int rt = 0; rt < 2; ++rt) {
      aR[ti][rt] = (f4){0.f, 0.f, 0.f, 0.f};
      aZ[ti][rt] = (f4){0.f, 0.f, 0.f, 0.f};
      aN[ti][rt] = (f4){0.f, 0.f, 0.f, 0.f};
      aHN[ti][rt] = (f4){0.f, 0.f, 0.f, 0.f};
    }
  #pragma unroll
  for (int ti = 0; ti < 2; ++ti) {
    const int col = ((w + 4 * ti) << 4) + bn;  // 0..127
    const ushort_t* W2 = ws + WS_W2;
    #pragma unroll
    for (int k0 = 0; k0 < 128; k0 += 32) {
      bf8 b0 = *(const bf8*)&W2[(size_t)(col) * 128 + k0 + kq];
      bf8 b1 = *(const bf8*)&W2[(size_t)(128 + col) * 128 + k0 + kq];
      bf8 bm = *(const bf8*)&W2[(size_t)(256 + col) * 128 + k0 + kq];
      #pragma unroll
      for (int rt = 0; rt < 2; ++rt) {
        bf8 a = *(const bf8*)&sR2[(rt * 16 + bn) * STH + k0 + kq];
        aR[ti][rt] = MFMA(a, b0, aR[ti][rt]);
        aZ[ti][rt] = MFMA(a, b1, aZ[ti][rt]);
        aHN[ti][rt] = MFMA(a, bm, aHN[ti][rt]);
      }
    }
    const ushort_t* W1 = ws + WS_W1;
    #pragma unroll
    for (int k0 = 0; k0 < 320; k0 += 32) {
      bf8 b0 = *(const bf8*)&W1[(size_t)(col) * 320 + k0 + kq];
      bf8 b1 = *(const bf8*)&W1[(size_t)(128 + col) * 320 + k0 + kq];
      bf8 bm = *(const bf8*)&W1[(size_t)(256 + col) * 320 + k0 + kq];
      #pragma unroll
      for (int rt = 0; rt < 2; ++rt) {
        bf8 a = *(const bf8*)&sA[(rt * 16 + bn) * STA + k0 + kq];
        aR[ti][rt] = MFMA(a, b0, aR[ti][rt]);
        aZ[ti][rt] = MFMA(a, b1, aZ[ti][rt]);
        aN[ti][rt] = MFMA(a, bm, aN[ti][rt]);
      }
    }
  }
  __syncthreads();  // B2 (all sR2/sA frag reads done)

  // ph3: GRU elementwise -> sR2 in-place + out[200:328]
  #pragma unroll
  for (int ti = 0; ti < 2; ++ti) {
    const int col = ((w + 4 * ti) << 4) + bn;
    float brr = con_b_ih[col] + con_b_hh[col];
    float brz = con_b_ih[128 + col] + con_b_hh[128 + col];
    float bin = con_b_ih[256 + col], bhn = con_b_hh[256 + col];
    #pragma unroll
    for (int rt = 0; rt < 2; ++rt) {
      #pragma unroll
      for (int j = 0; j < 4; ++j) {
        int row = rt * 16 + qrow + j;
        float hold = bf2f(sR2[row * STH + col]);
        float rr = sigf(aR[ti][rt][j] + brr);
        float zz = sigf(aZ[ti][rt][j] + brz);
        float nn = tanhf_(aN[ti][rt][j] + bin + rr * (aHN[ti][rt][j] + bhn));
        float hv = (1.f - zz) * nn + zz * hold;
        hv = fminf(fmaxf(hv, -5.f), 5.f);
        sR2[row * STH + col] = f2bf(hv);  // own (row,col): no race
        out[(size_t)(rbase + row) * HD + 200 + col] = hv;
      }
    }
  }
  __syncthreads();  // B3

  // ph4: co linear + reparam -> out[328:340]
  {
    int crow = tid >> 3, cn = tid & 7;
    float acc = co_b[cn];
    #pragma unroll 8
    for (int k0 = 0; k0 < 128; k0 += 4) {
      f4 hv = bf2f4(*(const us4*)&sR2[crow * STH + k0]);
      f4 wv = *(const f4*)&co_w[cn * 128 + k0];
      acc = fmaf(hv.x, wv.x, acc);
      acc = fmaf(hv.y, wv.y, acc);
      acc = fmaf(hv.z, wv.z, acc);
      acc = fmaf(hv.w, wv.w, acc);
    }
    float lv = __shfl(acc, lane + 4, 64);  // partner lane holds logvar
    if (cn < 4) {
      float stdv = __expf(0.5f * lv);
      float ov = fmaf(stdv, eps[(size_t)(rbase + crow) * 4 + cn], acc);
      size_t orow = (size_t)(rbase + crow) * HD;
      out[orow + 328 + cn] = acc;
      out[orow + 332 + cn] = stdv;
      out[orow + 336 + cn] = ov;
    }
  }
}

// ================= K2: generator GRU + factor =================
__global__ __launch_bounds__(256, 4) void gen_kernel(
    const float* __restrict__ h0,
    const float* __restrict__ gen_b_ih, const float* __restrict__ gen_b_hh,
    const ushort_t* __restrict__ ws, float* out)
{
  __shared__ __align__(16) unsigned char spool[29696];
  ushort_t* sGo = (ushort_t*)(spool);          // [32][216] gen_state_old
  ushort_t* sGn = (ushort_t*)(spool + 13824);  // [32][216] gen_state_new
  ushort_t* sGI = (ushort_t*)(spool + 27648);  // [32][32]  gen_input

  const int tid = threadIdx.x;
  const int rbase = blockIdx.x * 32;
  const int lane = tid & 63;
  const int w = tid >> 6;             // 0..3
  const int bn = lane & 15;
  const int kq = (lane >> 4) << 3;
  const int qrow = (lane >> 4) << 2;

  // ph1: stage gen_state_old (h0[0:200] + pad), gen_input (out[336:356]),
  // and ZERO the entire sGn region: 32*216 = 6912 ushorts = 1728 us4 chunks
  // (us4 = 8 bytes). R16 wrote only 864 chunks (half) -> rows 16-31 pad
  // stayed uninit-NaN and factor's k>=200 frags gave NaN*0=NaN.
  #pragma unroll
  for (int it = 0; it < 7; ++it) {
    int idx = tid + it * 256;
    if (idx < 1728) {
      us4 z = {0, 0, 0, 0};
      *(us4*)&sGn[idx << 2] = z;
    }
  }
  for (int idx = tid; idx < 32 * 54; idx += 256) {
    int r = idx / 54, u = idx - (idx / 54) * 54;
    if (u < 50) {
      f4 v = *(const f4*)&h0[(size_t)(rbase + r) * HD + (u << 2)];
      *(us4*)&sGo[r * STG + (u << 2)] = f2bf4(v);
    } else {
      us4 z = {0, 0, 0, 0};
      *(us4*)&sGo[r * STG + 200 + ((u - 50) << 2)] = z;  // gh K-pad
    }
  }
  if (tid < 160) {  // out[:,336:356] (gen_input f32) -> sGI cols 0..20
    int r = tid / 5, q = tid - (tid / 5) * 5;
    f4 v = *(const f4*)&out[(size_t)(rbase + r) * HD + 336 + (q << 2)];
    *(us4*)&sGI[r * 32 + (q << 2)] = f2bf4(v);
  } else if (tid < 256) {  // zero sGI cols 20..32 (gi K-pad)
    int t2 = tid - 160;
    if (t2 < 96) {
      int r = t2 / 3, q3 = t2 - (t2 / 3) * 3;
      us4 z = {0, 0, 0, 0};
      *(us4*)&sGI[r * 32 + 20 + (q3 << 2)] = z;
    }
  }
  __syncthreads();  // B1

  // ph2: gen GRU (13 col-tiles over 4 waves), epilogue per tile
  {
    const ushort_t* W3 = ws + WS_W3;
    const ushort_t* W4 = ws + WS_W4;
    for (int t = w; t < 13; t += 4) {
      int c = (t << 4) + bn;  // output column (valid < 200)
      f4 gR[2], gZ[2], gN[2], gHN[2];
      #pragma unroll
      for (int rt = 0; rt < 2; ++rt) {
        gR[rt] = (f4){0.f, 0.f, 0.f, 0.f};
        gZ[rt] = (f4){0.f, 0.f, 0.f, 0.f};
        gN[rt] = (f4){0.f, 0.f, 0.f, 0.f};
        gHN[rt] = (f4){0.f, 0.f, 0.f, 0.f};
      }
      {  // gi (K=32)
        bf8 b0 = *(const bf8*)&W3[(size_t)(c) * 32 + kq];
        bf8 b1 = *(const bf8*)&W3[(size_t)(200 + c) * 32 + kq];
        bf8 bm = *(const bf8*)&W3[(size_t)(400 + c) * 32 + kq];
        #pragma unroll
        for (int rt = 0; rt < 2; ++rt) {
          bf8 a = *(const bf8*)&sGI[(rt * 16 + bn) * 32 + kq];
          gR[rt] = MFMA(a, b0, gR[rt]);
          gZ[rt] = MFMA(a, b1, gZ[rt]);
          gN[rt] = MFMA(a, bm, gN[rt]);
        }
      }
      #pragma unroll
      for (int k0 = 0; k0 < 224; k0 += 32) {  // gh (K=200 padded)
        bf8 b0 = *(const bf8*)&W4[(size_t)(c) * 224 + k0 + kq];
        bf8 b1 = *(const bf8*)&W4[(size_t)(200 + c) * 224 + k0 + kq];
        bf8 bm = *(const bf8*)&W4[(size_t)(400 + c) * 224 + k0 + kq];
        #pragma unroll
        for (int rt = 0; rt < 2; ++rt) {
          bf8 a = *(const bf8*)&sGo[(rt * 16 + bn) * STG + k0 + kq];
          gR[rt] = MFMA(a, b0, gR[rt]);
          gZ[rt] = MFMA(a, b1, gZ[rt]);
          gHN[rt] = MFMA(a, bm, gHN[rt]);
        }
      }
      if (c < 200) {
        float brr = gen_b_ih[c] + gen_b_hh[c];
        float brz = gen_b_ih[200 + c] + gen_b_hh[200 + c];
        float bin = gen_b_ih[400 + c], bhn = gen_b_hh[400 + c];
        #pragma unroll
        for (int rt = 0; rt < 2; ++rt) {
          #pragma unroll
          for (int j = 0; j < 4; ++j) {
            int row = rt * 16 + qrow + j;
            float hold = bf2f(sGo[row * STG + c]);
            float rr = sigf(gR[rt][j] + brr);
            float zz = sigf(gZ[rt][j] + brz);
            float nn = tanhf_(gN[rt][j] + bin + rr * (gHN[rt][j] + bhn));
            float hv = (1.f - zz) * nn + zz * hold;
            hv = fminf(fmaxf(hv, -5.f), 5.f);
            sGn[row * STG + c] = f2bf(hv);
            out[(size_t)(rbase + row) * HD + c] = hv;
          }
        }
      }
    }
  }
  __syncthreads();  // B2

  // ph3: factor = gen_state_new @ normed_fac^T -> out[356:420]
  {
    const ushort_t* W5 = ws + WS_W5;
    int rt = w & 1;
    #pragma unroll
    for (int cc = 0; cc < 2; ++cc) {
      int ct = (w >> 1) + 2 * cc;  // 0..3
      f4 acc = (f4){0.f, 0.f, 0.f, 0.f};
      #pragma unroll
      for (int k0 = 0; k0 < 224; k0 += 32) {
        bf8 b = *(const bf8*)&W5[(size_t)((ct << 4) + bn) * 224 + k0 + kq];
        bf8 a = *(const bf8*)&sGn[(rt * 16 + bn) * STG + k0 + kq];
        acc = MFMA(a, b, acc);
      }
      #pragma unroll
      for (int j = 0; j < 4; ++j) {
        int row = rt * 16 + qrow + j;
        out[(size_t)(rbase + row) * HD + 356 + (ct << 4) + bn] = acc[j];
      }
    }
  }
}

extern "C" void kernel_launch(void* const* d_in, const int* in_sizes, int n_in,
                              void* d_out, int out_size, void* d_ws, size_t ws_size,
                              hipStream_t stream) {
  const float* x        = (const float*)d_in[0];
  const float* h0       = (const float*)d_in[1];
  const float* eps      = (const float*)d_in[2];
  const float* gen_w_ih = (const float*)d_in[3];
  const float* gen_w_hh = (const float*)d_in[4];
  const float* gen_b_ih = (const float*)d_in[5];
  const float* gen_b_hh = (const float*)d_in[6];
  const float* con_w_ih = (const float*)d_in[7];
  const float* con_w_hh = (const float*)d_in[8];
  const float* con_b_ih = (const float*)d_in[9];
  const float* con_b_hh = (const float*)d_in[10];
  const float* co_w     = (const float*)d_in[11];
  const float* co_b     = (const float*)d_in[12];
  const float* fac_w    = (const float*)d_in[13];
  float* out = (float*)d_out;
  ushort_t* ws = (ushort_t*)d_ws;

  hipLaunchKernelGGL(prep_w, dim3(256), dim3(512), 0, stream,
                     con_w_ih, con_w_hh, gen_w_ih, gen_w_hh, ws);
  hipLaunchKernelGGL(prep_fac, dim3(64), dim3(64), 0, stream, fac_w, ws);

  int nrows = in_sizes[2] / 4;  // eps is (B,4)
  int grid = nrows / 32;        // 2048
  hipLaunchKernelGGL(con_kernel, dim3(grid), dim3(256), 0, stream,
                     x, h0, eps, con_b_ih, con_b_hh, co_w, co_b, ws, out);
  hipLaunchKernelGGL(gen_kernel, dim3(grid), dim3(256), 0, stream,
                     h0, gen_b_ih, gen_b_hh, ws, out);
}

// Round 18
// 158.411 us; speedup vs baseline: 1.3650x; 1.3650x over previous
//
#include <hip/hip_runtime.h>
#include <math.h>

// DecoderCell fused kernel — FINAL (revert to R14, best measured: 151.7us).
// Structure: RT=128/NT=512, one block/CU; bf16-MFMA GEMMs with weights
// pre-converted to bf16 in d_ws (prep kernels); single-pass weight reads;
// rcp-based sigmoid/tanh; direct f32 epilogue stores (no flush phases);
// rolled K-loops. 8.8x over the f32 VALU baseline (1338us -> 151.7us).
// Refuted levers (R5-R17): occupancy, MLP, VALU count, LDS conflicts,
// store pattern, I$, phase/kernel splitting, 32x32 MFMA shape.

#define NT 512
#define RT 128
#define XD 272
#define HD 420

typedef unsigned short ushort_t;
typedef __attribute__((ext_vector_type(8))) short bf8;
typedef __attribute__((ext_vector_type(4))) float f4;
typedef __attribute__((ext_vector_type(4))) unsigned short us4;

// ws layout (bf16 element offsets)
#define WS_W1 0         // con_w_ih [384][320]
#define WS_W2 122880    // con_w_hh [384][128]
#define WS_W3 172032    // gen_w_ih [608][32]  (K 20->32 pad, rows 600-607 zero)
#define WS_W4 191488    // gen_w_hh [608][224] (K 200->224 pad, rows 600-607 zero)
#define WS_W5 327680    // normed fac_w [64][224] (K pad zero)

#define STA 328
#define STG 216
#define STH 136
#define STR3 88

#define O_A   0        // sA [128][328] = 83,968 ; later sGo [128][216]=55,296
#define O_GN  55296    // sGn [128][216] = 55,296
#define O_R2  83968    // sR2 [128][136] = 34,816
#define O_R3  118784   // sR3 [128][88]  = 22,528
#define POOLB 141312

__device__ __forceinline__ ushort_t f2bf(float f) {
  union { float f; unsigned u; } v; v.f = f;
  unsigned r = v.u + 0x7FFFu + ((v.u >> 16) & 1u);
  return (ushort_t)(r >> 16);
}
__device__ __forceinline__ float bf2f(ushort_t u) {
  union { unsigned u; float f; } v; v.u = ((unsigned)u) << 16; return v.f;
}
__device__ __forceinline__ us4 f2bf4(f4 v) {
  us4 b; b.x = f2bf(v.x); b.y = f2bf(v.y); b.z = f2bf(v.z); b.w = f2bf(v.w); return b;
}
__device__ __forceinline__ f4 bf2f4(us4 b) {
  f4 v; v.x = bf2f(b.x); v.y = bf2f(b.y); v.z = bf2f(b.z); v.w = bf2f(b.w); return v;
}
__device__ __forceinline__ float rcpf(float x) { return __builtin_amdgcn_rcpf(x); }
__device__ __forceinline__ float sigf(float x) { return rcpf(1.0f + __expf(-x)); }
__device__ __forceinline__ float tanhf_(float x) {
  return 1.0f - 2.0f * rcpf(1.0f + __expf(2.0f * x));
}

#define MFMA(a, b, c) __builtin_amdgcn_mfma_f32_16x16x32_bf16((a), (b), (c), 0, 0, 0)

__global__ void prep_w(const float* __restrict__ cw1, const float* __restrict__ cw2,
                       const float* __restrict__ gw3, const float* __restrict__ gw4,
                       ushort_t* __restrict__ ws) {
  int tid = blockIdx.x * blockDim.x + threadIdx.x;
  int np = gridDim.x * blockDim.x;
  for (int i = tid; i < 384 * 320; i += np) ws[WS_W1 + i] = f2bf(cw1[i]);
  for (int i = tid; i < 384 * 128; i += np) ws[WS_W2 + i] = f2bf(cw2[i]);
  for (int i = tid; i < 608 * 32; i += np) {
    int n = i >> 5, k = i & 31;
    ws[WS_W3 + i] = (n < 600 && k < 20) ? f2bf(gw3[n * 20 + k]) : (ushort_t)0;
  }
  for (int i = tid; i < 608 * 224; i += np) {
    int n = i / 224, k = i - n * 224;
    ws[WS_W4 + i] = (n < 600 && k < 200) ? f2bf(gw4[n * 200 + k]) : (ushort_t)0;
  }
}

__global__ void prep_fac(const float* __restrict__ fw, ushort_t* __restrict__ ws) {
  int n = blockIdx.x;   // 64 rows
  int l = threadIdx.x;  // 64 lanes
  float ss = 0.f;
  for (int k = l; k < 200; k += 64) { float v = fw[n * 200 + k]; ss = fmaf(v, v, ss); }
  for (int off = 32; off; off >>= 1) ss += __shfl_down(ss, off, 64);
  ss = __shfl(ss, 0, 64);
  float inv = 1.0f / fmaxf(sqrtf(ss), 1e-12f);
  for (int k = l; k < 224; k += 64)
    ws[WS_W5 + n * 224 + k] = (k < 200) ? f2bf(fw[n * 200 + k] * inv) : (ushort_t)0;
}

__global__ __launch_bounds__(NT, 2) void decoder_kernel(
    const float* __restrict__ x, const float* __restrict__ h0, const float* __restrict__ eps,
    const float* __restrict__ gen_b_ih, const float* __restrict__ gen_b_hh,
    const float* __restrict__ con_b_ih, const float* __restrict__ con_b_hh,
    const float* __restrict__ co_w, const float* __restrict__ co_b,
    const ushort_t* __restrict__ ws, float* __restrict__ out)
{
  __shared__ __align__(16) unsigned char spool[POOLB];
  ushort_t* sA  = (ushort_t*)(spool + O_A);    // con_input [128][328]
  ushort_t* sGo = (ushort_t*)(spool + O_A);    // gen_state_old [128][216]
  ushort_t* sGn = (ushort_t*)(spool + O_GN);   // gen_state_new [128][216]
  ushort_t* sR2 = (ushort_t*)(spool + O_R2);   // con_state bf16 [128][136]
  ushort_t* sR3 = (ushort_t*)(spool + O_R3);   // gen_input [128][88] (cols 0..32)

  const int tid = threadIdx.x;
  const int rbase = blockIdx.x * RT;
  const int lane = tid & 63;
  const int w = tid >> 6;
  const int bn = lane & 15;           // frag row/col within 16
  const int kq = (lane >> 4) << 3;    // k offset of quarter-wave
  const int qrow = (lane >> 4) << 2;  // C/D row offset of quarter-wave

  // ---------------- ph1: stage con_input, con_state, factor; ext -> out
  #pragma unroll
  for (int it = 0; it < 16; ++it) {  // x[:,0:256] -> sA
    int idx = tid + it * NT;
    int r = idx >> 6, c4 = (idx & 63) << 2;
    f4 v = *(const f4*)&x[(size_t)(rbase + r) * XD + c4];
    *(us4*)&sA[r * STA + c4] = f2bf4(v);
  }
  {  // x[:,256:272] -> sR3 cols 4..20 (gen_input ext) + direct out store
    int r = tid >> 2, e = (tid & 3) << 2;
    f4 v = *(const f4*)&x[(size_t)(rbase + r) * XD + 256 + e];
    *(us4*)&sR3[r * STR3 + 4 + e] = f2bf4(v);
    *(f4*)&out[(size_t)(rbase + r) * HD + 340 + e] = v;
  }
  #pragma unroll
  for (int it = 0; it < 8; ++it) {  // h0[:,200:328] -> sR2 (con_state_old)
    int idx = tid + it * NT;
    int r = idx >> 5, c4 = (idx & 31) << 2;
    f4 v = *(const f4*)&h0[(size_t)(rbase + r) * HD + 200 + c4];
    *(us4*)&sR2[r * STH + c4] = f2bf4(v);
  }
  #pragma unroll
  for (int it = 0; it < 4; ++it) {  // h0[:,356:420] -> sA cols 256..320
    int idx = tid + it * NT;
    int r = idx >> 4, c4 = (idx & 15) << 2;
    f4 v = *(const f4*)&h0[(size_t)(rbase + r) * HD + 356 + c4];
    *(us4*)&sA[r * STA + 256 + c4] = f2bf4(v);
  }
  if (tid < 384) {  // zero sR3 cols 20..32 (gi K-pad)
    int r = tid / 3, q = (tid - (tid / 3) * 3) << 2;
    us4 z = {0, 0, 0, 0};
    *(us4*)&sR3[r * STR3 + 20 + q] = z;
  }
  __syncthreads();  // B1

  const int col = (w << 4) + bn;  // wave's con output column (0..127)

  // ---------------- ph2: con GEMMs (8 row-tiles/wave), I$-resident loops
  f4 aR[8], aZ[8], aN[8], aHN[8];
  #pragma unroll
  for (int ri = 0; ri < 8; ++ri) {
    aR[ri] = (f4){0.f, 0.f, 0.f, 0.f};
    aZ[ri] = (f4){0.f, 0.f, 0.f, 0.f};
    aN[ri] = (f4){0.f, 0.f, 0.f, 0.f};
    aHN[ri] = (f4){0.f, 0.f, 0.f, 0.f};
  }
  {
    const ushort_t* W2 = ws + WS_W2;
    #pragma unroll 1
    for (int k0 = 0; k0 < 128; k0 += 32) {  // gh (K=128)
      bf8 b0 = *(const bf8*)&W2[(size_t)(col) * 128 + k0 + kq];
      bf8 b1 = *(const bf8*)&W2[(size_t)(128 + col) * 128 + k0 + kq];
      bf8 bm = *(const bf8*)&W2[(size_t)(256 + col) * 128 + k0 + kq];
      #pragma unroll
      for (int ri = 0; ri < 8; ++ri) {
        bf8 a = *(const bf8*)&sR2[(ri * 16 + bn) * STH + k0 + kq];
        aR[ri] = MFMA(a, b0, aR[ri]);
        aZ[ri] = MFMA(a, b1, aZ[ri]);
        aHN[ri] = MFMA(a, bm, aHN[ri]);
      }
    }
    const ushort_t* W1 = ws + WS_W1;
    #pragma unroll 1
    for (int k0 = 0; k0 < 320; k0 += 32) {  // gi (K=320)
      bf8 b0 = *(const bf8*)&W1[(size_t)(col) * 320 + k0 + kq];
      bf8 b1 = *(const bf8*)&W1[(size_t)(128 + col) * 320 + k0 + kq];
      bf8 bm = *(const bf8*)&W1[(size_t)(256 + col) * 320 + k0 + kq];
      #pragma unroll
      for (int ri = 0; ri < 8; ++ri) {
        bf8 a = *(const bf8*)&sA[(ri * 16 + bn) * STA + k0 + kq];
        aR[ri] = MFMA(a, b0, aR[ri]);
        aZ[ri] = MFMA(a, b1, aZ[ri]);
        aN[ri] = MFMA(a, bm, aN[ri]);
      }
    }
  }
  __syncthreads();  // B2 (sA + sR2 frag reads done)

  // ---------------- ph3: stage gen_state_old (over dead sA) || con epilogue
  #pragma unroll 1
  for (int idx = tid; idx < 128 * 54; idx += NT) {
    int r = idx / 54, u = idx - (idx / 54) * 54;
    if (u < 50) {
      f4 v = *(const f4*)&h0[(size_t)(rbase + r) * HD + (u << 2)];
      *(us4*)&sGo[r * STG + (u << 2)] = f2bf4(v);
    } else {
      us4 z = {0, 0, 0, 0};
      *(us4*)&sGo[r * STG + 200 + ((u - 50) << 2)] = z;  // gh K-pad
    }
  }
  {
    float brr = con_b_ih[col] + con_b_hh[col];
    float brz = con_b_ih[128 + col] + con_b_hh[128 + col];
    float bin = con_b_ih[256 + col], bhn = con_b_hh[256 + col];
    #pragma unroll
    for (int ri = 0; ri < 8; ++ri) {
      #pragma unroll
      for (int j = 0; j < 4; ++j) {
        int row = ri * 16 + qrow + j;
        float hold = bf2f(sR2[row * STH + col]);
        float rr = sigf(aR[ri][j] + brr);
        float zz = sigf(aZ[ri][j] + brz);
        float nn = tanhf_(aN[ri][j] + bin + rr * (aHN[ri][j] + bhn));
        float hv = (1.f - zz) * nn + zz * hold;
        hv = fminf(fmaxf(hv, -5.f), 5.f);
        sR2[row * STH + col] = f2bf(hv);  // own (row,col) only: no race
        out[(size_t)(rbase + row) * HD + 200 + col] = hv;  // direct store
      }
    }
  }
  __syncthreads();  // B3

  // ---------------- ph4: co linear + reparam (f32 VALU; 128 rows x 8 cols)
  {
    int cn = tid & 7;
    #pragma unroll
    for (int half = 0; half < 2; ++half) {
      int crow = (tid >> 3) + half * 64;
      float acc = co_b[cn];
      #pragma unroll 8
      for (int k0 = 0; k0 < 128; k0 += 4) {
        f4 hv = bf2f4(*(const us4*)&sR2[crow * STH + k0]);
        f4 wv = *(const f4*)&co_w[cn * 128 + k0];
        acc = fmaf(hv.x, wv.x, acc);
        acc = fmaf(hv.y, wv.y, acc);
        acc = fmaf(hv.z, wv.z, acc);
        acc = fmaf(hv.w, wv.w, acc);
      }
      float lv = __shfl(acc, lane + 4, 64);  // partner lane holds logvar
      if (cn < 4) {
        float stdv = __expf(0.5f * lv);
        float ov = fmaf(stdv, eps[(size_t)(rbase + crow) * 4 + cn], acc);
        size_t orow = (size_t)(rbase + crow) * HD;
        out[orow + 328 + cn] = acc;
        out[orow + 332 + cn] = stdv;
        out[orow + 336 + cn] = ov;
        sR3[crow * STR3 + cn] = f2bf(ov);
      }
    }
  }
  __syncthreads();  // B4 (sR2 reads done; sGn may now overwrite its alias)

  // ---------------- ph6: gen GRU (13 col-tiles over 8 waves)
  {  // zero sGn K-pad cols 200..216
    int r = tid >> 2, q = (tid & 3) << 2;
    us4 z = {0, 0, 0, 0};
    *(us4*)&sGn[r * STG + 200 + q] = z;
  }
  {
    const ushort_t* W3 = ws + WS_W3;
    const ushort_t* W4 = ws + WS_W4;
    #pragma unroll 1
    for (int t = w; t < 13; t += 8) {
      int c = (t << 4) + bn;  // output column (valid < 200)
      f4 gR[8], gZ[8], gN[8], gHN[8];
      #pragma unroll
      for (int ri = 0; ri < 8; ++ri) {
        gR[ri] = (f4){0.f, 0.f, 0.f, 0.f};
        gZ[ri] = (f4){0.f, 0.f, 0.f, 0.f};
        gN[ri] = (f4){0.f, 0.f, 0.f, 0.f};
        gHN[ri] = (f4){0.f, 0.f, 0.f, 0.f};
      }
      {  // gi (K=32)
        bf8 b0 = *(const bf8*)&W3[(size_t)(c) * 32 + kq];
        bf8 b1 = *(const bf8*)&W3[(size_t)(200 + c) * 32 + kq];
        bf8 bm = *(const bf8*)&W3[(size_t)(400 + c) * 32 + kq];
        #pragma unroll
        for (int ri = 0; ri < 8; ++ri) {
          bf8 a = *(const bf8*)&sR3[(ri * 16 + bn) * STR3 + kq];
          gR[ri] = MFMA(a, b0, gR[ri]);
          gZ[ri] = MFMA(a, b1, gZ[ri]);
          gN[ri] = MFMA(a, bm, gN[ri]);
        }
      }
      #pragma unroll 1
      for (int k0 = 0; k0 < 224; k0 += 32) {  // gh (K=200 padded)
        bf8 b0 = *(const bf8*)&W4[(size_t)(c) * 224 + k0 + kq];
        bf8 b1 = *(const bf8*)&W4[(size_t)(200 + c) * 224 + k0 + kq];
        bf8 bm = *(const bf8*)&W4[(size_t)(400 + c) * 224 + k0 + kq];
        #pragma unroll
        for (int ri = 0; ri < 8; ++ri) {
          bf8 a = *(const bf8*)&sGo[(ri * 16 + bn) * STG + k0 + kq];
          gR[ri] = MFMA(a, b0, gR[ri]);
          gZ[ri] = MFMA(a, b1, gZ[ri]);
          gHN[ri] = MFMA(a, bm, gHN[ri]);
        }
      }
      if (c < 200) {
        float brr = gen_b_ih[c] + gen_b_hh[c];
        float brz = gen_b_ih[200 + c] + gen_b_hh[200 + c];
        float bin = gen_b_ih[400 + c], bhn = gen_b_hh[400 + c];
        #pragma unroll
        for (int ri = 0; ri < 8; ++ri) {
          #pragma unroll
          for (int j = 0; j < 4; ++j) {
            int row = ri * 16 + qrow + j;
            float hold = bf2f(sGo[row * STG + c]);
            float rr = sigf(gR[ri][j] + brr);
            float zz = sigf(gZ[ri][j] + brz);
            float nn = tanhf_(gN[ri][j] + bin + rr * (gHN[ri][j] + bhn));
            float hv = (1.f - zz) * nn + zz * hold;
            hv = fminf(fmaxf(hv, -5.f), 5.f);
            sGn[row * STG + c] = f2bf(hv);
            out[(size_t)(rbase + row) * HD + c] = hv;  // direct store
          }
        }
      }
    }
  }
  __syncthreads();  // B6

  // ---------------- ph7: factor = gen_state_new @ normed_fac^T -> out direct
  {
    const ushort_t* W5 = ws + WS_W5;
    #pragma unroll 1
    for (int job = 0; job < 4; ++job) {
      int ri = ((w & 3) << 1) + (job & 1);      // 0..7
      int ct = ((w >> 2) << 1) + (job >> 1);    // 0..3
      bf8 w5f[7];
      #pragma unroll
      for (int k = 0; k < 7; ++k)
        w5f[k] = *(const bf8*)&W5[(size_t)((ct << 4) + bn) * 224 + k * 32 + kq];
      f4 acc = (f4){0.f, 0.f, 0.f, 0.f};
      #pragma unroll
      for (int k = 0; k < 7; ++k) {
        bf8 a = *(const bf8*)&sGn[(ri * 16 + bn) * STG + k * 32 + kq];
        acc = MFMA(a, w5f[k], acc);
      }
      #pragma unroll
      for (int j = 0; j < 4; ++j) {
        int row = ri * 16 + qrow + j;
        out[(size_t)(rbase + row) * HD + 356 + (ct << 4) + bn] = acc[j];
      }
    }
  }
}

extern "C" void kernel_launch(void* const* d_in, const int* in_sizes, int n_in,
                              void* d_out, int out_size, void* d_ws, size_t ws_size,
                              hipStream_t stream) {
  const float* x        = (const float*)d_in[0];
  const float* h0       = (const float*)d_in[1];
  const float* eps      = (const float*)d_in[2];
  const float* gen_w_ih = (const float*)d_in[3];
  const float* gen_w_hh = (const float*)d_in[4];
  const float* gen_b_ih = (const float*)d_in[5];
  const float* gen_b_hh = (const float*)d_in[6];
  const float* con_w_ih = (const float*)d_in[7];
  const float* con_w_hh = (const float*)d_in[8];
  const float* con_b_ih = (const float*)d_in[9];
  const float* con_b_hh = (const float*)d_in[10];
  const float* co_w     = (const float*)d_in[11];
  const float* co_b     = (const float*)d_in[12];
  const float* fac_w    = (const float*)d_in[13];
  float* out = (float*)d_out;
  ushort_t* ws = (ushort_t*)d_ws;

  hipLaunchKernelGGL(prep_w, dim3(256), dim3(512), 0, stream,
                     con_w_ih, con_w_hh, gen_w_ih, gen_w_hh, ws);
  hipLaunchKernelGGL(prep_fac, dim3(64), dim3(64), 0, stream, fac_w, ws);

  int nrows = in_sizes[2] / 4;  // eps is (B,4)
  int grid = nrows / RT;        // 512
  hipLaunchKernelGGL(decoder_kernel, dim3(grid), dim3(NT), 0, stream,
                     x, h0, eps, gen_b_ih, gen_b_hh, con_b_ih, con_b_hh,
                     co_w, co_b, ws, out);
}

// Round 19
// 143.162 us; speedup vs baseline: 1.5103x; 1.1065x over previous
//
#include <hip/hip_runtime.h>
#include <math.h>

// DecoderCell fused kernel — Round 19: R14 structure with FRAGMENT-MAJOR
// weight layout. Theory: the occupancy/MLP/VALU/LDS/I$-invariant stall is
// TA address-divergence — each B-frag load was 64 lanes x 16B at stride
// 640/448B = 64 scattered cache lines per instruction (~944 loads/block x
// 64 lines ~ 50us/CU hidden). prep_frag rewrites weights so each fragment
// is a contiguous 1KB record: loads become wave-contiguous bursts (16
// sequential lines). Pure permutation; decoder GEMM structure unchanged.

#define NT 512
#define RT 128
#define XD 272
#define HD 420

typedef unsigned short ushort_t;
typedef __attribute__((ext_vector_type(8))) short bf8;
typedef __attribute__((ext_vector_type(4))) float f4;
typedef __attribute__((ext_vector_type(4))) unsigned short us4;

// ws layout (bf16 element offsets) — fragment-major:
// frag = 512 bf16 = 1KB; element (frag, lane, e) at frag*512 + lane*8 + e.
#define WS_CONF 0        // 336 frags: (w*14 + c)*3 + g ; c<4=gh(W2), c>=4=gi(W1)
#define WS_GENF 172032   // 312 frags: (t*8 + c)*3 + g  ; c==0=gi(W3), c>=1=gh(W4)
#define WS_FACF 331776   // 28 frags:  ct*7 + c          (normalized fac_w)
#define WS_INV  346112   // 64 floats (128 ushorts): per-row 1/||fac_w||

#define STA 328
#define STG 216
#define STH 136
#define STR3 88

#define O_A   0        // sA [128][328] = 83,968 ; later sGo [128][216]=55,296
#define O_GN  55296    // sGn [128][216] = 55,296
#define O_R2  83968    // sR2 [128][136] = 34,816
#define O_R3  118784   // sR3 [128][88]  = 22,528
#define POOLB 141312

__device__ __forceinline__ ushort_t f2bf(float f) {
  union { float f; unsigned u; } v; v.f = f;
  unsigned r = v.u + 0x7FFFu + ((v.u >> 16) & 1u);
  return (ushort_t)(r >> 16);
}
__device__ __forceinline__ float bf2f(ushort_t u) {
  union { unsigned u; float f; } v; v.u = ((unsigned)u) << 16; return v.f;
}
__device__ __forceinline__ us4 f2bf4(f4 v) {
  us4 b; b.x = f2bf(v.x); b.y = f2bf(v.y); b.z = f2bf(v.z); b.w = f2bf(v.w); return b;
}
__device__ __forceinline__ f4 bf2f4(us4 b) {
  f4 v; v.x = bf2f(b.x); v.y = bf2f(b.y); v.z = bf2f(b.z); v.w = bf2f(b.w); return v;
}
__device__ __forceinline__ float rcpf(float x) { return __builtin_amdgcn_rcpf(x); }
__device__ __forceinline__ float sigf(float x) { return rcpf(1.0f + __expf(-x)); }
__device__ __forceinline__ float tanhf_(float x) {
  return 1.0f - 2.0f * rcpf(1.0f + __expf(2.0f * x));
}

#define MFMA(a, b, c) __builtin_amdgcn_mfma_f32_16x16x32_bf16((a), (b), (c), 0, 0, 0)

__global__ void prep_inv(const float* __restrict__ fw, ushort_t* __restrict__ ws) {
  int n = blockIdx.x;   // 64 rows
  int l = threadIdx.x;  // 64 lanes
  float ss = 0.f;
  for (int k = l; k < 200; k += 64) { float v = fw[n * 200 + k]; ss = fmaf(v, v, ss); }
  for (int off = 32; off; off >>= 1) ss += __shfl_down(ss, off, 64);
  ss = __shfl(ss, 0, 64);
  if (l == 0) ((float*)(ws + WS_INV))[n] = 1.0f / fmaxf(sqrtf(ss), 1e-12f);
}

__global__ void prep_frag(const float* __restrict__ cw1, const float* __restrict__ cw2,
                          const float* __restrict__ gw3, const float* __restrict__ gw4,
                          const float* __restrict__ fw, ushort_t* __restrict__ ws) {
  const float* inv = (const float*)(ws + WS_INV);
  int tid = blockIdx.x * blockDim.x + threadIdx.x;
  int np = gridDim.x * blockDim.x;
  // CONF: wave wv, chunk c (0-3 gh over W2, 4-13 gi over W1), gate g.
  for (int i = tid; i < 336 * 512; i += np) {
    int f = i >> 9, u = i & 511;
    int l = u >> 3, e = u & 7;
    int g = f % 3, cw = f / 3;
    int c = cw % 14, wv = cw / 14;
    int col = wv * 16 + (l & 15);
    int krel = ((l >> 4) << 3) + e;
    float v = (c < 4) ? cw2[(size_t)(g * 128 + col) * 128 + c * 32 + krel]
                      : cw1[(size_t)(g * 128 + col) * 320 + (c - 4) * 32 + krel];
    ws[WS_CONF + i] = f2bf(v);
  }
  // GENF: tile t, chunk c (0 = gi over W3 K=32pad, 1-7 = gh over W4), gate g.
  for (int i = tid; i < 312 * 512; i += np) {
    int f = i >> 9, u = i & 511;
    int l = u >> 3, e = u & 7;
    int g = f % 3, tc = f / 3;
    int c = tc & 7, t = tc >> 3;
    int col = t * 16 + (l & 15);
    int krel = ((l >> 4) << 3) + e;
    float v = 0.f;
    if (col < 200) {
      if (c == 0) { if (krel < 20) v = gw3[(size_t)(g * 200 + col) * 20 + krel]; }
      else { int k = (c - 1) * 32 + krel; if (k < 200) v = gw4[(size_t)(g * 200 + col) * 200 + k]; }
    }
    ws[WS_GENF + i] = f2bf(v);
  }
  // FACF: col-tile ct, chunk c; normalized rows, K zero-padded to 224.
  for (int i = tid; i < 28 * 512; i += np) {
    int f = i >> 9, u = i & 511;
    int l = u >> 3, e = u & 7;
    int c = f % 7, ct = f / 7;
    int col = ct * 16 + (l & 15);
    int k = c * 32 + ((l >> 4) << 3) + e;
    float v = (k < 200) ? fw[(size_t)col * 200 + k] * inv[col] : 0.f;
    ws[WS_FACF + i] = f2bf(v);
  }
}

__global__ __launch_bounds__(NT, 2) void decoder_kernel(
    const float* __restrict__ x, const float* __restrict__ h0, const float* __restrict__ eps,
    const float* __restrict__ gen_b_ih, const float* __restrict__ gen_b_hh,
    const float* __restrict__ con_b_ih, const float* __restrict__ con_b_hh,
    const float* __restrict__ co_w, const float* __restrict__ co_b,
    const ushort_t* __restrict__ ws, float* __restrict__ out)
{
  __shared__ __align__(16) unsigned char spool[POOLB];
  ushort_t* sA  = (ushort_t*)(spool + O_A);    // con_input [128][328]
  ushort_t* sGo = (ushort_t*)(spool + O_A);    // gen_state_old [128][216]
  ushort_t* sGn = (ushort_t*)(spool + O_GN);   // gen_state_new [128][216]
  ushort_t* sR2 = (ushort_t*)(spool + O_R2);   // con_state bf16 [128][136]
  ushort_t* sR3 = (ushort_t*)(spool + O_R3);   // gen_input [128][88] (cols 0..32)

  const int tid = threadIdx.x;
  const int rbase = blockIdx.x * RT;
  const int lane = tid & 63;
  const int w = tid >> 6;
  const int bn = lane & 15;           // frag row/col within 16
  const int kq = (lane >> 4) << 3;    // k offset of quarter-wave
  const int qrow = (lane >> 4) << 2;  // C/D row offset of quarter-wave

  // ---------------- ph1: stage con_input, con_state, factor; ext -> out
  #pragma unroll
  for (int it = 0; it < 16; ++it) {  // x[:,0:256] -> sA
    int idx = tid + it * NT;
    int r = idx >> 6, c4 = (idx & 63) << 2;
    f4 v = *(const f4*)&x[(size_t)(rbase + r) * XD + c4];
    *(us4*)&sA[r * STA + c4] = f2bf4(v);
  }
  {  // x[:,256:272] -> sR3 cols 4..20 (gen_input ext) + direct out store
    int r = tid >> 2, e = (tid & 3) << 2;
    f4 v = *(const f4*)&x[(size_t)(rbase + r) * XD + 256 + e];
    *(us4*)&sR3[r * STR3 + 4 + e] = f2bf4(v);
    *(f4*)&out[(size_t)(rbase + r) * HD + 340 + e] = v;
  }
  #pragma unroll
  for (int it = 0; it < 8; ++it) {  // h0[:,200:328] -> sR2 (con_state_old)
    int idx = tid + it * NT;
    int r = idx >> 5, c4 = (idx & 31) << 2;
    f4 v = *(const f4*)&h0[(size_t)(rbase + r) * HD + 200 + c4];
    *(us4*)&sR2[r * STH + c4] = f2bf4(v);
  }
  #pragma unroll
  for (int it = 0; it < 4; ++it) {  // h0[:,356:420] -> sA cols 256..320
    int idx = tid + it * NT;
    int r = idx >> 4, c4 = (idx & 15) << 2;
    f4 v = *(const f4*)&h0[(size_t)(rbase + r) * HD + 356 + c4];
    *(us4*)&sA[r * STA + 256 + c4] = f2bf4(v);
  }
  if (tid < 384) {  // zero sR3 cols 20..32 (gi K-pad)
    int r = tid / 3, q = (tid - (tid / 3) * 3) << 2;
    us4 z = {0, 0, 0, 0};
    *(us4*)&sR3[r * STR3 + 20 + q] = z;
  }
  __syncthreads();  // B1

  const int col = (w << 4) + bn;  // wave's con output column (0..127)

  // ---------------- ph2: con GEMMs (8 row-tiles/wave), coalesced frag loads
  f4 aR[8], aZ[8], aN[8], aHN[8];
  #pragma unroll
  for (int ri = 0; ri < 8; ++ri) {
    aR[ri] = (f4){0.f, 0.f, 0.f, 0.f};
    aZ[ri] = (f4){0.f, 0.f, 0.f, 0.f};
    aN[ri] = (f4){0.f, 0.f, 0.f, 0.f};
    aHN[ri] = (f4){0.f, 0.f, 0.f, 0.f};
  }
  {
    const ushort_t* CF = ws + WS_CONF;
    const size_t wb = (size_t)(w * 42) * 512 + (size_t)lane * 8;  // w*14*3 frags
    #pragma unroll 1
    for (int c = 0; c < 4; ++c) {  // gh (K=128)
      int k0 = c * 32;
      bf8 b0 = *(const bf8*)&CF[wb + (size_t)(c * 3 + 0) * 512];
      bf8 b1 = *(const bf8*)&CF[wb + (size_t)(c * 3 + 1) * 512];
      bf8 bm = *(const bf8*)&CF[wb + (size_t)(c * 3 + 2) * 512];
      #pragma unroll
      for (int ri = 0; ri < 8; ++ri) {
        bf8 a = *(const bf8*)&sR2[(ri * 16 + bn) * STH + k0 + kq];
        aR[ri] = MFMA(a, b0, aR[ri]);
        aZ[ri] = MFMA(a, b1, aZ[ri]);
        aHN[ri] = MFMA(a, bm, aHN[ri]);
      }
    }
    #pragma unroll 1
    for (int c = 4; c < 14; ++c) {  // gi (K=320)
      int k0 = (c - 4) * 32;
      bf8 b0 = *(const bf8*)&CF[wb + (size_t)(c * 3 + 0) * 512];
      bf8 b1 = *(const bf8*)&CF[wb + (size_t)(c * 3 + 1) * 512];
      bf8 bm = *(const bf8*)&CF[wb + (size_t)(c * 3 + 2) * 512];
      #pragma unroll
      for (int ri = 0; ri < 8; ++ri) {
        bf8 a = *(const bf8*)&sA[(ri * 16 + bn) * STA + k0 + kq];
        aR[ri] = MFMA(a, b0, aR[ri]);
        aZ[ri] = MFMA(a, b1, aZ[ri]);
        aN[ri] = MFMA(a, bm, aN[ri]);
      }
    }
  }
  __syncthreads();  // B2 (sA + sR2 frag reads done)

  // ---------------- ph3: stage gen_state_old (over dead sA) || con epilogue
  #pragma unroll 1
  for (int idx = tid; idx < 128 * 54; idx += NT) {
    int r = idx / 54, u = idx - (idx / 54) * 54;
    if (u < 50) {
      f4 v = *(const f4*)&h0[(size_t)(rbase + r) * HD + (u << 2)];
      *(us4*)&sGo[r * STG + (u << 2)] = f2bf4(v);
    } else {
      us4 z = {0, 0, 0, 0};
      *(us4*)&sGo[r * STG + 200 + ((u - 50) << 2)] = z;  // gh K-pad
    }
  }
  {
    float brr = con_b_ih[col] + con_b_hh[col];
    float brz = con_b_ih[128 + col] + con_b_hh[128 + col];
    float bin = con_b_ih[256 + col], bhn = con_b_hh[256 + col];
    #pragma unroll
    for (int ri = 0; ri < 8; ++ri) {
      #pragma unroll
      for (int j = 0; j < 4; ++j) {
        int row = ri * 16 + qrow + j;
        float hold = bf2f(sR2[row * STH + col]);
        float rr = sigf(aR[ri][j] + brr);
        float zz = sigf(aZ[ri][j] + brz);
        float nn = tanhf_(aN[ri][j] + bin + rr * (aHN[ri][j] + bhn));
        float hv = (1.f - zz) * nn + zz * hold;
        hv = fminf(fmaxf(hv, -5.f), 5.f);
        sR2[row * STH + col] = f2bf(hv);  // own (row,col) only: no race
        out[(size_t)(rbase + row) * HD + 200 + col] = hv;  // direct store
      }
    }
  }
  __syncthreads();  // B3

  // ---------------- ph4: co linear + reparam (f32 VALU; 128 rows x 8 cols)
  {
    int cn = tid & 7;
    #pragma unroll
    for (int half = 0; half < 2; ++half) {
      int crow = (tid >> 3) + half * 64;
      float acc = co_b[cn];
      #pragma unroll 8
      for (int k0 = 0; k0 < 128; k0 += 4) {
        f4 hv = bf2f4(*(const us4*)&sR2[crow * STH + k0]);
        f4 wv = *(const f4*)&co_w[cn * 128 + k0];
        acc = fmaf(hv.x, wv.x, acc);
        acc = fmaf(hv.y, wv.y, acc);
        acc = fmaf(hv.z, wv.z, acc);
        acc = fmaf(hv.w, wv.w, acc);
      }
      float lv = __shfl(acc, lane + 4, 64);  // partner lane holds logvar
      if (cn < 4) {
        float stdv = __expf(0.5f * lv);
        float ov = fmaf(stdv, eps[(size_t)(rbase + crow) * 4 + cn], acc);
        size_t orow = (size_t)(rbase + crow) * HD;
        out[orow + 328 + cn] = acc;
        out[orow + 332 + cn] = stdv;
        out[orow + 336 + cn] = ov;
        sR3[crow * STR3 + cn] = f2bf(ov);
      }
    }
  }
  __syncthreads();  // B4 (sR2 reads done; sGn may now overwrite its alias)

  // ---------------- ph6: gen GRU (13 col-tiles over 8 waves)
  {  // zero sGn K-pad cols 200..216
    int r = tid >> 2, q = (tid & 3) << 2;
    us4 z = {0, 0, 0, 0};
    *(us4*)&sGn[r * STG + 200 + q] = z;
  }
  {
    const ushort_t* GF = ws + WS_GENF;
    #pragma unroll 1
    for (int t = w; t < 13; t += 8) {
      int c = (t << 4) + bn;  // output column (valid < 200)
      const size_t gb = (size_t)(t * 24) * 512 + (size_t)lane * 8;  // t*8*3 frags
      f4 gR[8], gZ[8], gN[8], gHN[8];
      #pragma unroll
      for (int ri = 0; ri < 8; ++ri) {
        gR[ri] = (f4){0.f, 0.f, 0.f, 0.f};
        gZ[ri] = (f4){0.f, 0.f, 0.f, 0.f};
        gN[ri] = (f4){0.f, 0.f, 0.f, 0.f};
        gHN[ri] = (f4){0.f, 0.f, 0.f, 0.f};
      }
      {  // gi (K=32, chunk 0)
        bf8 b0 = *(const bf8*)&GF[gb + 0 * 512];
        bf8 b1 = *(const bf8*)&GF[gb + 1 * 512];
        bf8 bm = *(const bf8*)&GF[gb + 2 * 512];
        #pragma unroll
        for (int ri = 0; ri < 8; ++ri) {
          bf8 a = *(const bf8*)&sR3[(ri * 16 + bn) * STR3 + kq];
          gR[ri] = MFMA(a, b0, gR[ri]);
          gZ[ri] = MFMA(a, b1, gZ[ri]);
          gN[ri] = MFMA(a, bm, gN[ri]);
        }
      }
      #pragma unroll 1
      for (int cc = 1; cc < 8; ++cc) {  // gh (K=200 padded, chunks 1..7)
        int k0 = (cc - 1) * 32;
        bf8 b0 = *(const bf8*)&GF[gb + (size_t)(cc * 3 + 0) * 512];
        bf8 b1 = *(const bf8*)&GF[gb + (size_t)(cc * 3 + 1) * 512];
        bf8 bm = *(const bf8*)&GF[gb + (size_t)(cc * 3 + 2) * 512];
        #pragma unroll
        for (int ri = 0; ri < 8; ++ri) {
          bf8 a = *(const bf8*)&sGo[(ri * 16 + bn) * STG + k0 + kq];
          gR[ri] = MFMA(a, b0, gR[ri]);
          gZ[ri] = MFMA(a, b1, gZ[ri]);
          gHN[ri] = MFMA(a, bm, gHN[ri]);
        }
      }
      if (c < 200) {
        float brr = gen_b_ih[c] + gen_b_hh[c];
        float brz = gen_b_ih[200 + c] + gen_b_hh[200 + c];
        float bin = gen_b_ih[400 + c], bhn = gen_b_hh[400 + c];
        #pragma unroll
        for (int ri = 0; ri < 8; ++ri) {
          #pragma unroll
          for (int j = 0; j < 4; ++j) {
            int row = ri * 16 + qrow + j;
            float hold = bf2f(sGo[row * STG + c]);
            float rr = sigf(gR[ri][j] + brr);
            float zz = sigf(gZ[ri][j] + brz);
            float nn = tanhf_(gN[ri][j] + bin + rr * (gHN[ri][j] + bhn));
            float hv = (1.f - zz) * nn + zz * hold;
            hv = fminf(fmaxf(hv, -5.f), 5.f);
            sGn[row * STG + c] = f2bf(hv);
            out[(size_t)(rbase + row) * HD + c] = hv;  // direct store
          }
        }
      }
    }
  }
  __syncthreads();  // B6

  // ---------------- ph7: factor = gen_state_new @ normed_fac^T -> out direct
  {
    const ushort_t* FF = ws + WS_FACF;
    #pragma unroll 1
    for (int job = 0; job < 4; ++job) {
      int ri = ((w & 3) << 1) + (job & 1);      // 0..7
      int ct = ((w >> 2) << 1) + (job >> 1);    // 0..3
      bf8 w5f[7];
      #pragma unroll
      for (int k = 0; k < 7; ++k)
        w5f[k] = *(const bf8*)&FF[(size_t)(ct * 7 + k) * 512 + (size_t)lane * 8];
      f4 acc = (f4){0.f, 0.f, 0.f, 0.f};
      #pragma unroll
      for (int k = 0; k < 7; ++k) {
        bf8 a = *(const bf8*)&sGn[(ri * 16 + bn) * STG + k * 32 + kq];
        acc = MFMA(a, w5f[k], acc);
      }
      #pragma unroll
      for (int j = 0; j < 4; ++j) {
        int row = ri * 16 + qrow + j;
        out[(size_t)(rbase + row) * HD + 356 + (ct << 4) + bn] = acc[j];
      }
    }
  }
}

extern "C" void kernel_launch(void* const* d_in, const int* in_sizes, int n_in,
                              void* d_out, int out_size, void* d_ws, size_t ws_size,
                              hipStream_t stream) {
  const float* x        = (const float*)d_in[0];
  const float* h0       = (const float*)d_in[1];
  const float* eps      = (const float*)d_in[2];
  const float* gen_w_ih = (const float*)d_in[3];
  const float* gen_w_hh = (const float*)d_in[4];
  const float* gen_b_ih = (const float*)d_in[5];
  const float* gen_b_hh = (const float*)d_in[6];
  const float* con_w_ih = (const float*)d_in[7];
  const float* con_w_hh = (const float*)d_in[8];
  const float* con_b_ih = (const float*)d_in[9];
  const float* con_b_hh = (const float*)d_in[10];
  const float* co_w     = (const float*)d_in[11];
  const float* co_b     = (const float*)d_in[12];
  const float* fac_w    = (const float*)d_in[13];
  float* out = (float*)d_out;
  ushort_t* ws = (ushort_t*)d_ws;

  hipLaunchKernelGGL(prep_inv, dim3(64), dim3(64), 0, stream, fac_w, ws);
  hipLaunchKernelGGL(prep_frag, dim3(256), dim3(512), 0, stream,
                     con_w_ih, con_w_hh, gen_w_ih, gen_w_hh, fac_w, ws);

  int nrows = in_sizes[2] / 4;  // eps is (B,4)
  int grid = nrows / RT;        // 512
  hipLaunchKernelGGL(decoder_kernel, dim3(grid), dim3(NT), 0, stream,
                     x, h0, eps, gen_b_ih, gen_b_hh, con_b_ih, con_b_hh,
                     co_w, co_b, ws, out);
}